// Round 1
// baseline (602.695 us; speedup 1.0000x reference)
//
#include <hip/hip_runtime.h>
#include <stdint.h>

// ---------------------------------------------------------------------------
// out[n_tok, out_f] = input @ (w_scale * round(weight))^T + b_scale*round(bias)
// M=8192 (tokens), N=4096 (out_f), K=4096 (in_f), all fp32 in HBM.
//
// Strategy: round(weight) is a small integer -> EXACT in bf16. input->bf16
// costs ~2^-9 rel err -> output absmax ~0.4 << 2.18 threshold. So:
//   1) cvt kernels: input fp32->bf16, round(weight) fp32->bf16 into d_ws
//   2) m97-structure bf16 MFMA GEMM (128x128 tile, BK=32, global_load_lds x16)
// Scale + bias applied in fp32 epilogue (w_q stays exact through MFMA).
// ---------------------------------------------------------------------------

using bf16x8  = __attribute__((ext_vector_type(8))) __bf16;
using floatx4 = __attribute__((ext_vector_type(4))) float;
using ushort8 = __attribute__((ext_vector_type(8))) unsigned short;

__device__ __forceinline__ unsigned short f2bf_rne(float x) {
    unsigned int u = __float_as_uint(x);
    // round-to-nearest-even bf16 (inputs are finite normals; no NaN handling)
    return (unsigned short)((u + 0x7fffu + ((u >> 16) & 1u)) >> 16);
}

__device__ __forceinline__ void load_lds16(const unsigned short* g, unsigned short* l) {
    // lane i of the wave lands at l + i*16 bytes; l must be wave-uniform
    __builtin_amdgcn_global_load_lds(
        (__attribute__((address_space(1))) void*)g,
        (__attribute__((address_space(3))) void*)l,
        16, 0, 0);
}

// ---------------------------------------------------------------------------
// fp32 -> bf16 conversion, 8 elems/thread, 32B loads / 16B stores.
// ROUND=true applies rintf (straight-through round, matches jnp.round RNE).
// ---------------------------------------------------------------------------
template <bool ROUND>
__global__ __launch_bounds__(256) void cvt_bf16(const float* __restrict__ in,
                                                unsigned short* __restrict__ out) {
    const long long i = ((long long)blockIdx.x * 256 + threadIdx.x) * 8;
    float4 v0 = *(const float4*)(in + i);
    float4 v1 = *(const float4*)(in + i + 4);
    float f[8] = {v0.x, v0.y, v0.z, v0.w, v1.x, v1.y, v1.z, v1.w};
    ushort8 o;
#pragma unroll
    for (int j = 0; j < 8; ++j) {
        float x = ROUND ? rintf(f[j]) : f[j];
        o[j] = f2bf_rne(x);
    }
    *(ushort8*)(out + i) = o;
}

// ---------------------------------------------------------------------------
// bf16 GEMM, B transposed layout (both A and B are K-contiguous).
// Block = 256 thr = 4 waves, tile 128x128, BK=32. Wave w -> 64x64 subtile at
// (wm,wn) = ((w>>1)*64, (w&1)*64); 4x4 grid of 16x16x32 MFMA accumulators.
// LDS: unpadded row-major [128][32] bf16 (8 KB each) -- required contiguous
// in lane order for global_load_lds (wave-uniform base + lane*16B).
// ---------------------------------------------------------------------------
__global__ __launch_bounds__(256) void gemm_bf16_bt(
    const unsigned short* __restrict__ A,   // [M][K] bf16 (input)
    const unsigned short* __restrict__ B,   // [N][K] bf16 (round(weight), exact)
    const float* __restrict__ bias,
    const float* __restrict__ wscale_p,
    const float* __restrict__ bscale_p,
    float* __restrict__ C,                  // [M][N] fp32
    int M, int N, int K) {
    constexpr int BM = 128, BN = 128, BK = 32;
    __shared__ unsigned short ldsA[BM * BK];   // 8 KB
    __shared__ unsigned short ldsB[BN * BK];   // 8 KB

    const int tid  = threadIdx.x;
    const int wave = tid >> 6;
    const int lane = tid & 63;
    const int quad = lane >> 4;
    const int l16  = lane & 15;

    const int bm = blockIdx.y * BM;
    const int bn = blockIdx.x * BN;
    const int wm = (wave >> 1) * 64;
    const int wn = (wave & 1) * 64;

    const float wsc = wscale_p[0];
    const float bsc = bscale_p[0];

    // bias contribution: per lane, col n depends only on ni
    float badd[4];
#pragma unroll
    for (int ni = 0; ni < 4; ++ni)
        badd[ni] = bsc * rintf(bias[bn + wn + ni * 16 + l16]);

    // Staging: each tile = 512 x 16B chunks; chunk c -> row c>>2, k-off (c&3)*8.
    // Wave w stages chunks [w*128, w*128+128) in two 64-lane issues.
    const int c0 = wave * 128 + lane;
    const int c1 = c0 + 64;
    const int r0 = c0 >> 2, k0 = (c0 & 3) * 8;
    const int r1 = c1 >> 2, k1 = (c1 & 3) * 8;
    const unsigned short* gA0 = A + (size_t)(bm + r0) * K + k0;
    const unsigned short* gA1 = A + (size_t)(bm + r1) * K + k1;
    const unsigned short* gB0 = B + (size_t)(bn + r0) * K + k0;
    const unsigned short* gB1 = B + (size_t)(bn + r1) * K + k1;
    unsigned short* lA0 = &ldsA[(wave * 128 + 0) * 8];   // wave-uniform bases
    unsigned short* lA1 = &ldsA[(wave * 128 + 64) * 8];
    unsigned short* lB0 = &ldsB[(wave * 128 + 0) * 8];
    unsigned short* lB1 = &ldsB[(wave * 128 + 64) * 8];

    floatx4 acc[4][4] = {};

    for (int kt = 0; kt < K; kt += BK) {
        load_lds16(gA0 + kt, lA0);
        load_lds16(gA1 + kt, lA1);
        load_lds16(gB0 + kt, lB0);
        load_lds16(gB1 + kt, lB1);
        __syncthreads();   // drains vmcnt(0): LDS tiles complete

        // A-operand layout: lane holds A[m=l16][k=quad*8 + 0..7] (m120-verified)
        bf16x8 af[4], bfr[4];
#pragma unroll
        for (int mi = 0; mi < 4; ++mi) {
            const int off = (wm + mi * 16 + l16) * BK + quad * 8;
            af[mi] = __builtin_bit_cast(bf16x8, *(const ushort8*)&ldsA[off]);
        }
#pragma unroll
        for (int ni = 0; ni < 4; ++ni) {
            const int off = (wn + ni * 16 + l16) * BK + quad * 8;
            bfr[ni] = __builtin_bit_cast(bf16x8, *(const ushort8*)&ldsB[off]);
        }
#pragma unroll
        for (int mi = 0; mi < 4; ++mi)
#pragma unroll
            for (int ni = 0; ni < 4; ++ni)
                acc[mi][ni] = __builtin_amdgcn_mfma_f32_16x16x32_bf16(
                    af[mi], bfr[ni], acc[mi][ni], 0, 0, 0);
        __syncthreads();   // protect LDS from next iteration's staging
    }

    // Epilogue. C/D layout: row(m) = quad*4 + r, col(n) = l16 (m89/m91-verified)
#pragma unroll
    for (int mi = 0; mi < 4; ++mi) {
        const int m0 = bm + wm + mi * 16 + quad * 4;
#pragma unroll
        for (int ni = 0; ni < 4; ++ni) {
            const int n = bn + wn + ni * 16 + l16;
#pragma unroll
            for (int r = 0; r < 4; ++r)
                C[(size_t)(m0 + r) * N + n] = acc[mi][ni][r] * wsc + badd[ni];
        }
    }
}

// ---------------------------------------------------------------------------
// Safety-net fallback (only if d_ws is too small — not expected to trigger).
// ---------------------------------------------------------------------------
__global__ __launch_bounds__(256) void fallback_gemm(
    const float* __restrict__ A, const float* __restrict__ W,
    const float* __restrict__ bias, const float* __restrict__ wsp,
    const float* __restrict__ bsp, float* __restrict__ C, int M, int N, int K) {
    const int n = blockIdx.x * 256 + threadIdx.x;
    const int m = blockIdx.y;
    if (n >= N || m >= M) return;
    float s = 0.f;
    for (int k = 0; k < K; ++k)
        s += A[(size_t)m * K + k] * rintf(W[(size_t)n * K + k]);
    C[(size_t)m * N + n] = s * wsp[0] + bsp[0] * rintf(bias[n]);
}

extern "C" void kernel_launch(void* const* d_in, const int* in_sizes, int n_in,
                              void* d_out, int out_size, void* d_ws, size_t ws_size,
                              hipStream_t stream) {
    const float* input  = (const float*)d_in[0];
    const float* weight = (const float*)d_in[1];
    const float* bias   = (const float*)d_in[2];
    const float* wscale = (const float*)d_in[3];
    const float* bscale = (const float*)d_in[4];
    float* out = (float*)d_out;

    const int N = in_sizes[2];              // out_f = bias length (4096)
    const int K = in_sizes[1] / N;          // in_f  (4096)
    const int M = in_sizes[0] / K;          // n_tok (8192)

    const size_t needA = (size_t)M * K * sizeof(unsigned short);
    const size_t needB = (size_t)N * K * sizeof(unsigned short);

    if (ws_size >= needA + needB && (M % 128) == 0 && (N % 128) == 0 &&
        (K % 32) == 0 && ((size_t)M * K % 2048) == 0 && ((size_t)N * K % 2048) == 0) {
        unsigned short* Abf = (unsigned short*)d_ws;
        unsigned short* Bbf = (unsigned short*)((char*)d_ws + needA);
        cvt_bf16<false><<<(unsigned)((size_t)M * K / 2048), 256, 0, stream>>>(input, Abf);
        cvt_bf16<true ><<<(unsigned)((size_t)N * K / 2048), 256, 0, stream>>>(weight, Bbf);
        dim3 grid(N / 128, M / 128);
        gemm_bf16_bt<<<grid, 256, 0, stream>>>(Abf, Bbf, bias, wscale, bscale, out, M, N, K);
    } else {
        dim3 grid((N + 255) / 256, M);
        fallback_gemm<<<grid, 256, 0, stream>>>(input, weight, bias, wscale, bscale, out, M, N, K);
    }
}

// Round 3
// 594.645 us; speedup vs baseline: 1.0135x; 1.0135x over previous
//
#include <hip/hip_runtime.h>
#include <stdint.h>

// ---------------------------------------------------------------------------
// out[n_tok, out_f] = input @ (w_scale * round(weight))^T + b_scale*round(bias)
// M=8192, N=4096, K=4096, fp32 in/out.
//
// R1: 602 us total; gemm 379 us, SQ_LDS_BANK_CONFLICT=3.35e7 (~14% of gemm
// cycles — 8-way ds_read_b128 aliasing from 64B row stride), cvt slice slow.
// R2: (a) XOR-swizzle LDS chunk slots: global chunk (s ^ ((r>>1)&3)) lands in
//     slot s — fragment ds_read_b128 aliasing drops 8-way -> 2-way (free).
//     (b) cvt: fully coalesced (lane i <-> bytes i*16), one fused launch.
//     (build fix: ushort4/8 aliases renamed us4/us8 — HIP defines ushort4)
// ---------------------------------------------------------------------------

using bf16x8  = __attribute__((ext_vector_type(8))) __bf16;
using floatx4 = __attribute__((ext_vector_type(4))) float;
using us8     = __attribute__((ext_vector_type(8))) unsigned short;
using us4     = __attribute__((ext_vector_type(4))) unsigned short;

__device__ __forceinline__ unsigned short f2bf_rne(float x) {
    unsigned int u = __float_as_uint(x);
    return (unsigned short)((u + 0x7fffu + ((u >> 16) & 1u)) >> 16);
}

__device__ __forceinline__ void load_lds16(const unsigned short* g, unsigned short* l) {
    __builtin_amdgcn_global_load_lds(
        (__attribute__((address_space(1))) void*)g,
        (__attribute__((address_space(3))) void*)l,
        16, 0, 0);
}

// ---------------------------------------------------------------------------
// Fused fp32->bf16 conversion: A (identity) then B (rintf). Fully coalesced:
// thread i handles float4 #i (16B load, 8B store).
// ---------------------------------------------------------------------------
__global__ __launch_bounds__(256) void cvt_both(
    const float* __restrict__ inA, unsigned short* __restrict__ outA, long long nA4,
    const float* __restrict__ inB, unsigned short* __restrict__ outB, long long nB4) {
    const long long i = (long long)blockIdx.x * 256 + threadIdx.x;
    if (i < nA4) {
        float4 v = ((const float4*)inA)[i];
        us4 o = { f2bf_rne(v.x), f2bf_rne(v.y), f2bf_rne(v.z), f2bf_rne(v.w) };
        ((us4*)outA)[i] = o;
    } else {
        const long long j = i - nA4;
        if (j < nB4) {
            float4 v = ((const float4*)inB)[j];
            us4 o = { f2bf_rne(rintf(v.x)), f2bf_rne(rintf(v.y)),
                      f2bf_rne(rintf(v.z)), f2bf_rne(rintf(v.w)) };
            ((us4*)outB)[j] = o;
        }
    }
}

// ---------------------------------------------------------------------------
// bf16 GEMM, B^T layout. Block=256 (4 waves), tile 128x128, BK=32.
// LDS geometry: per tile, 512 chunks of 16B; LDS slot (row r, k-slot s)
// holds GLOBAL k-chunk (s ^ ((r>>1)&3)) — the XOR swizzle.
// ---------------------------------------------------------------------------
__global__ __launch_bounds__(256) void gemm_bf16_bt(
    const unsigned short* __restrict__ A,   // [M][K] bf16
    const unsigned short* __restrict__ B,   // [N][K] bf16 (exact ints)
    const float* __restrict__ bias,
    const float* __restrict__ wscale_p,
    const float* __restrict__ bscale_p,
    float* __restrict__ C,                  // [M][N] fp32
    int M, int N, int K) {
    constexpr int BM = 128, BK = 32;
    __shared__ unsigned short ldsA[BM * BK];
    __shared__ unsigned short ldsB[BM * BK];

    const int tid  = threadIdx.x;
    const int wave = tid >> 6;
    const int lane = tid & 63;
    const int quad = lane >> 4;
    const int l16  = lane & 15;

    const int bm = blockIdx.y * BM;
    const int bn = blockIdx.x * BM;
    const int wm = (wave >> 1) * 64;
    const int wn = (wave & 1) * 64;

    const float wsc = wscale_p[0];
    const float bsc = bscale_p[0];

    float badd[4];
#pragma unroll
    for (int ni = 0; ni < 4; ++ni)
        badd[ni] = bsc * rintf(bias[bn + wn + ni * 16 + l16]);

    // ---- staging addresses (two 64-lane issues per wave per tile) ----
    // LDS chunk index = wave*128 + issue*64 + lane; row r = idx>>2, slot s=lane&3.
    // Global k-chunk for this slot: s ^ ((r>>1)&3).  (r>>1)&3 == (lane>>3)&3
    // for both issues (row delta 16 -> r>>1 delta 8 ≡ 0 mod 4).
    const int r0 = wave * 32 + (lane >> 2);               // issue-0 row in tile
    const int kc = ((lane & 3) ^ ((lane >> 3) & 3)) * 8;  // k-offset (shorts)
    const unsigned short* gA0 = A + (size_t)(bm + r0) * K + kc;
    const unsigned short* gA1 = A + (size_t)(bm + r0 + 16) * K + kc;
    const unsigned short* gB0 = B + (size_t)(bn + r0) * K + kc;
    const unsigned short* gB1 = B + (size_t)(bn + r0 + 16) * K + kc;
    unsigned short* lA0 = &ldsA[(wave * 128 + 0) * 8];
    unsigned short* lA1 = &ldsA[(wave * 128 + 64) * 8];
    unsigned short* lB0 = &ldsB[(wave * 128 + 0) * 8];
    unsigned short* lB1 = &ldsB[(wave * 128 + 64) * 8];

    // ---- fragment-read swizzle: row = .. + l16, xr = (row>>1)&3 = (l16>>1)&3
    const int xr = (l16 >> 1) & 3;
    const int sa = (quad ^ xr) * 8;   // swizzled k-slot offset (shorts)

    floatx4 acc[4][4] = {};

    for (int kt = 0; kt < K; kt += BK) {
        load_lds16(gA0 + kt, lA0);
        load_lds16(gA1 + kt, lA1);
        load_lds16(gB0 + kt, lB0);
        load_lds16(gB1 + kt, lB1);
        __syncthreads();

        bf16x8 af[4], bfr[4];
#pragma unroll
        for (int mi = 0; mi < 4; ++mi) {
            const int off = (wm + mi * 16 + l16) * BK + sa;
            af[mi] = __builtin_bit_cast(bf16x8, *(const us8*)&ldsA[off]);
        }
#pragma unroll
        for (int ni = 0; ni < 4; ++ni) {
            const int off = (wn + ni * 16 + l16) * BK + sa;
            bfr[ni] = __builtin_bit_cast(bf16x8, *(const us8*)&ldsB[off]);
        }
#pragma unroll
        for (int mi = 0; mi < 4; ++mi)
#pragma unroll
            for (int ni = 0; ni < 4; ++ni)
                acc[mi][ni] = __builtin_amdgcn_mfma_f32_16x16x32_bf16(
                    af[mi], bfr[ni], acc[mi][ni], 0, 0, 0);
        __syncthreads();
    }

    // Epilogue. C/D layout: row(m)=quad*4+r, col(n)=l16.
#pragma unroll
    for (int mi = 0; mi < 4; ++mi) {
        const int m0 = bm + wm + mi * 16 + quad * 4;
#pragma unroll
        for (int ni = 0; ni < 4; ++ni) {
            const int n = bn + wn + ni * 16 + l16;
#pragma unroll
            for (int r = 0; r < 4; ++r)
                C[(size_t)(m0 + r) * N + n] = acc[mi][ni][r] * wsc + badd[ni];
        }
    }
}

// ---------------------------------------------------------------------------
// Fallback (only if d_ws too small — not expected).
// ---------------------------------------------------------------------------
__global__ __launch_bounds__(256) void fallback_gemm(
    const float* __restrict__ A, const float* __restrict__ W,
    const float* __restrict__ bias, const float* __restrict__ wsp,
    const float* __restrict__ bsp, float* __restrict__ C, int M, int N, int K) {
    const int n = blockIdx.x * 256 + threadIdx.x;
    const int m = blockIdx.y;
    if (n >= N || m >= M) return;
    float s = 0.f;
    for (int k = 0; k < K; ++k)
        s += A[(size_t)m * K + k] * rintf(W[(size_t)n * K + k]);
    C[(size_t)m * N + n] = s * wsp[0] + bsp[0] * rintf(bias[n]);
}

extern "C" void kernel_launch(void* const* d_in, const int* in_sizes, int n_in,
                              void* d_out, int out_size, void* d_ws, size_t ws_size,
                              hipStream_t stream) {
    const float* input  = (const float*)d_in[0];
    const float* weight = (const float*)d_in[1];
    const float* bias   = (const float*)d_in[2];
    const float* wscale = (const float*)d_in[3];
    const float* bscale = (const float*)d_in[4];
    float* out = (float*)d_out;

    const int N = in_sizes[2];
    const int K = in_sizes[1] / N;
    const int M = in_sizes[0] / K;

    const size_t needA = (size_t)M * K * sizeof(unsigned short);
    const size_t needB = (size_t)N * K * sizeof(unsigned short);

    if (ws_size >= needA + needB && (M % 128) == 0 && (N % 128) == 0 &&
        (K % 32) == 0) {
        unsigned short* Abf = (unsigned short*)d_ws;
        unsigned short* Bbf = (unsigned short*)((char*)d_ws + needA);
        const long long nA4 = (long long)M * K / 4;
        const long long nB4 = (long long)N * K / 4;
        const long long nthr = nA4 + nB4;
        cvt_both<<<(unsigned)((nthr + 255) / 256), 256, 0, stream>>>(
            input, Abf, nA4, weight, Bbf, nB4);
        dim3 grid(N / 128, M / 128);
        gemm_bf16_bt<<<grid, 256, 0, stream>>>(Abf, Bbf, bias, wscale, bscale, out, M, N, K);
    } else {
        dim3 grid((N + 255) / 256, M);
        fallback_gemm<<<grid, 256, 0, stream>>>(input, weight, bias, wscale, bscale, out, M, N, K);
    }
}

// Round 4
// 533.458 us; speedup vs baseline: 1.1298x; 1.1147x over previous
//
#include <hip/hip_runtime.h>
#include <stdint.h>

// ---------------------------------------------------------------------------
// out[n_tok, out_f] = input @ (w_scale * round(weight))^T + b_scale*round(bias)
// M=8192, N=4096, K=4096, fp32 in/out.
//
// R1: 602 us; gemm 379 us, 3.35e7 LDS conflicts. R3: XOR swizzle -> 0
// conflicts but NEUTRAL time (stalls were shadowed by barrier drain).
// GEMM sits at the m97-structure plateau (MfmaUtil 33 + VALU 47 + ~20% drain).
// R4: attack the two knobs NOT on the failed-tweaks list (m131-141):
//   (a) BK=64: halves barrier pairs (128->64); LDS 32 KB (not m132's 64 KB).
//   (b) 32x32x16 MFMA, 2x2 acc/wave: 4064 vs 3378 FLOP/cyc on the matrix
//       pipe, half the MFMA issue slots. Same ds_read bytes.
//   (c) swizzle generalized: LDS slot s of row r holds global chunk s^(r&7)
//       (8 chunks/row); staging stays span-coalesced, fragment reads uniform.
// ---------------------------------------------------------------------------

using bf16x8   = __attribute__((ext_vector_type(8))) __bf16;
using floatx16 = __attribute__((ext_vector_type(16))) float;
using us8      = __attribute__((ext_vector_type(8))) unsigned short;
using us4      = __attribute__((ext_vector_type(4))) unsigned short;

__device__ __forceinline__ unsigned short f2bf_rne(float x) {
    unsigned int u = __float_as_uint(x);
    return (unsigned short)((u + 0x7fffu + ((u >> 16) & 1u)) >> 16);
}

__device__ __forceinline__ void load_lds16(const unsigned short* g, unsigned short* l) {
    __builtin_amdgcn_global_load_lds(
        (__attribute__((address_space(1))) void*)g,
        (__attribute__((address_space(3))) void*)l,
        16, 0, 0);
}

// ---------------------------------------------------------------------------
// Fused fp32->bf16 conversion: A (identity) then B (rintf). Coalesced 16B/lane.
// ---------------------------------------------------------------------------
__global__ __launch_bounds__(256) void cvt_both(
    const float* __restrict__ inA, unsigned short* __restrict__ outA, long long nA4,
    const float* __restrict__ inB, unsigned short* __restrict__ outB, long long nB4) {
    const long long i = (long long)blockIdx.x * 256 + threadIdx.x;
    if (i < nA4) {
        float4 v = ((const float4*)inA)[i];
        us4 o = { f2bf_rne(v.x), f2bf_rne(v.y), f2bf_rne(v.z), f2bf_rne(v.w) };
        ((us4*)outA)[i] = o;
    } else {
        const long long j = i - nA4;
        if (j < nB4) {
            float4 v = ((const float4*)inB)[j];
            us4 o = { f2bf_rne(rintf(v.x)), f2bf_rne(rintf(v.y)),
                      f2bf_rne(rintf(v.z)), f2bf_rne(rintf(v.w)) };
            ((us4*)outB)[j] = o;
        }
    }
}

// ---------------------------------------------------------------------------
// bf16 GEMM, B^T layout. Block=256 (4 waves), tile 128x128, BK=64.
// Wave w -> 64x64 subtile; 2x2 grid of 32x32x16 MFMA accumulators.
// LDS: [128][64] shorts per matrix (16 KB); slot s of row r holds global
// k-chunk s ^ (r&7) (16B chunks, 8 per row).
// ---------------------------------------------------------------------------
__global__ __launch_bounds__(256) void gemm_bf16_bt(
    const unsigned short* __restrict__ A,   // [M][K] bf16
    const unsigned short* __restrict__ B,   // [N][K] bf16 (exact ints)
    const float* __restrict__ bias,
    const float* __restrict__ wscale_p,
    const float* __restrict__ bscale_p,
    float* __restrict__ C,                  // [M][N] fp32
    int M, int N, int K) {
    constexpr int BM = 128, BK = 64;
    __shared__ unsigned short ldsA[BM * BK];   // 16 KB
    __shared__ unsigned short ldsB[BM * BK];   // 16 KB

    const int tid  = threadIdx.x;
    const int wave = tid >> 6;
    const int lane = tid & 63;

    const int bm = blockIdx.y * BM;
    const int bn = blockIdx.x * BM;
    const int wm = (wave >> 1) * 64;
    const int wn = (wave & 1) * 64;

    const float wsc = wscale_p[0];
    const float bsc = bscale_p[0];

    const int col = lane & 31;                 // MFMA col / row-in-operand
    const int khalf = lane >> 5;               // 0/1: which K-half of operand

    float badd[2];
#pragma unroll
    for (int ni = 0; ni < 2; ++ni)
        badd[ni] = bsc * rintf(bias[bn + wn + ni * 32 + col]);

    // ---- staging: 1024 chunks/matrix; wave w, issue i covers chunks
    // c = w*256 + i*64 + lane -> row r = c>>3, slot s = lane&7,
    // global k-chunk g = s ^ (r&7) = (lane&7) ^ (lane>>3)   [r&7 == lane>>3]
    const int g_st = ((lane & 7) ^ (lane >> 3)) * 8;   // k-offset in shorts
    const unsigned short* gAp[4];
    const unsigned short* gBp[4];
    unsigned short* lA[4];
    unsigned short* lB[4];
#pragma unroll
    for (int i = 0; i < 4; ++i) {
        const int r = wave * 32 + i * 8 + (lane >> 3);
        gAp[i] = A + (size_t)(bm + r) * K + g_st;
        gBp[i] = B + (size_t)(bn + r) * K + g_st;
        lA[i] = &ldsA[(wave * 256 + i * 64) * 8];
        lB[i] = &ldsB[(wave * 256 + i * 64) * 8];
    }

    floatx16 acc[2][2] = {};

    for (int kt = 0; kt < K; kt += BK) {
#pragma unroll
        for (int i = 0; i < 4; ++i) {
            load_lds16(gAp[i] + kt, lA[i]);
            load_lds16(gBp[i] + kt, lB[i]);
        }
        __syncthreads();

        // fragment rows: r = (wm|wn) + mi*32 + col  ->  r&7 == lane&7
#pragma unroll
        for (int ks = 0; ks < 4; ++ks) {
            const int gc = ks * 2 + khalf;              // global chunk 0..7
            const int slot = (gc ^ (lane & 7)) * 8;     // short offset in row
            bf16x8 af[2], bfr[2];
#pragma unroll
            for (int mi = 0; mi < 2; ++mi) {
                const int off = (wm + mi * 32 + col) * BK + slot;
                af[mi] = __builtin_bit_cast(bf16x8, *(const us8*)&ldsA[off]);
            }
#pragma unroll
            for (int ni = 0; ni < 2; ++ni) {
                const int off = (wn + ni * 32 + col) * BK + slot;
                bfr[ni] = __builtin_bit_cast(bf16x8, *(const us8*)&ldsB[off]);
            }
#pragma unroll
            for (int mi = 0; mi < 2; ++mi)
#pragma unroll
                for (int ni = 0; ni < 2; ++ni)
                    acc[mi][ni] = __builtin_amdgcn_mfma_f32_32x32x16_bf16(
                        af[mi], bfr[ni], acc[mi][ni], 0, 0, 0);
        }
        __syncthreads();
    }

    // Epilogue. 32x32 C/D layout (m74/m101): col = lane&31,
    // row = (reg&3) + 8*(reg>>2) + 4*(lane>>5).
    const int rbase = 4 * khalf;
#pragma unroll
    for (int mi = 0; mi < 2; ++mi) {
#pragma unroll
        for (int ni = 0; ni < 2; ++ni) {
            const int n = bn + wn + ni * 32 + col;
#pragma unroll
            for (int reg = 0; reg < 16; ++reg) {
                const int m = bm + wm + mi * 32 + (reg & 3) + 8 * (reg >> 2) + rbase;
                C[(size_t)m * N + n] = acc[mi][ni][reg] * wsc + badd[ni];
            }
        }
    }
}

// ---------------------------------------------------------------------------
// Fallback (only if d_ws too small — not expected).
// ---------------------------------------------------------------------------
__global__ __launch_bounds__(256) void fallback_gemm(
    const float* __restrict__ A, const float* __restrict__ W,
    const float* __restrict__ bias, const float* __restrict__ wsp,
    const float* __restrict__ bsp, float* __restrict__ C, int M, int N, int K) {
    const int n = blockIdx.x * 256 + threadIdx.x;
    const int m = blockIdx.y;
    if (n >= N || m >= M) return;
    float s = 0.f;
    for (int k = 0; k < K; ++k)
        s += A[(size_t)m * K + k] * rintf(W[(size_t)n * K + k]);
    C[(size_t)m * N + n] = s * wsp[0] + bsp[0] * rintf(bias[n]);
}

extern "C" void kernel_launch(void* const* d_in, const int* in_sizes, int n_in,
                              void* d_out, int out_size, void* d_ws, size_t ws_size,
                              hipStream_t stream) {
    const float* input  = (const float*)d_in[0];
    const float* weight = (const float*)d_in[1];
    const float* bias   = (const float*)d_in[2];
    const float* wscale = (const float*)d_in[3];
    const float* bscale = (const float*)d_in[4];
    float* out = (float*)d_out;

    const int N = in_sizes[2];
    const int K = in_sizes[1] / N;
    const int M = in_sizes[0] / K;

    const size_t needA = (size_t)M * K * sizeof(unsigned short);
    const size_t needB = (size_t)N * K * sizeof(unsigned short);

    if (ws_size >= needA + needB && (M % 128) == 0 && (N % 128) == 0 &&
        (K % 64) == 0) {
        unsigned short* Abf = (unsigned short*)d_ws;
        unsigned short* Bbf = (unsigned short*)((char*)d_ws + needA);
        const long long nA4 = (long long)M * K / 4;
        const long long nB4 = (long long)N * K / 4;
        const long long nthr = nA4 + nB4;
        cvt_both<<<(unsigned)((nthr + 255) / 256), 256, 0, stream>>>(
            input, Abf, nA4, weight, Bbf, nB4);
        dim3 grid(N / 128, M / 128);
        gemm_bf16_bt<<<grid, 256, 0, stream>>>(Abf, Bbf, bias, wscale, bscale, out, M, N, K);
    } else {
        dim3 grid((N + 255) / 256, M);
        fallback_gemm<<<grid, 256, 0, stream>>>(input, weight, bias, wscale, bscale, out, M, N, K);
    }
}